// Round 8
// baseline (387.185 us; speedup 1.0000x reference)
//
#include <hip/hip_runtime.h>

// Problem constants: N=50000, E=600000, F=128, H=128, O=64, R=8
#define F_DIM 128
#define H_DIM 128
#define O_DIM 64
#define R_NUM 8

typedef __attribute__((ext_vector_type(8))) short bf16x8;
typedef __attribute__((ext_vector_type(4))) float f32x4;

union V8 { bf16x8 v; short4 h[2]; };

__device__ __forceinline__ unsigned short f2b(float f) {
    unsigned u = __float_as_uint(f);
    u += 0x7FFFu + ((u >> 16) & 1u);   // RNE
    return (unsigned short)(u >> 16);
}
__device__ __forceinline__ float b2f(unsigned short b) {
    return __uint_as_float(((unsigned)b) << 16);
}

// ---- fused setup A: (dst,rel) degree count + per-block ew min/max ;
//      x -> bf16 ; both weight stacks transpose+convert. Grid MUST be 512. ----
__global__ __launch_bounds__(256) void setupA(
    const float* __restrict__ ew, const int* __restrict__ dst,
    const int* __restrict__ et, int E, int* __restrict__ deg2,
    float* __restrict__ bmn, float* __restrict__ bmx,
    const float* __restrict__ x, unsigned short* __restrict__ xb, long x4,
    const float* __restrict__ W1, const float* __restrict__ root1,
    const float* __restrict__ W2, const float* __restrict__ root2,
    unsigned short* __restrict__ wt1, unsigned short* __restrict__ wt2) {
    __shared__ float smn[256], smx[256];
    const int tid = threadIdx.x;
    const int gstride = gridDim.x * blockDim.x;
    int g0 = blockIdx.x * blockDim.x + tid;

    // phase 1: degree count + minmax partials
    float mn = 1e30f, mx = -1e30f;
    for (int i = g0; i < E; i += gstride) {
        atomicAdd(&deg2[dst[i] * R_NUM + et[i]], 1);
        float v = ew[i];
        mn = fminf(mn, v);
        mx = fmaxf(mx, v);
    }
    smn[tid] = mn; smx[tid] = mx;
    __syncthreads();
    for (int s = 128; s > 0; s >>= 1) {
        if (tid < s) {
            smn[tid] = fminf(smn[tid], smn[tid + s]);
            smx[tid] = fmaxf(smx[tid], smx[tid + s]);
        }
        __syncthreads();
    }
    if (tid == 0) { bmn[blockIdx.x] = smn[0]; bmx[blockIdx.x] = smx[0]; }

    // phase 2: x -> bf16 (float4 groups)
    for (long i = g0; i < x4; i += gstride) {
        float4 v = ((const float4*)x)[i];
        ushort4 o;
        o.x = f2b(v.x); o.y = f2b(v.y); o.z = f2b(v.z); o.w = f2b(v.w);
        ((ushort4*)xb)[i] = o;
    }

    // phase 3: weights -> transposed bf16
    const int n1 = 9 * 128 * 128, n2 = 9 * 64 * 128;
    for (int idx = g0; idx < n1 + n2; idx += gstride) {
        if (idx < n1) {
            int r = idx / (128 * 128), rem = idx % (128 * 128);
            int n = rem / 128, k = rem % 128;
            float v = (r < 8) ? W1[((size_t)r * 128 + k) * 128 + n]
                              : root1[(size_t)k * 128 + n];
            wt1[idx] = f2b(v);
        } else {
            int j = idx - n1;
            int r = j / (64 * 128), rem = j % (64 * 128);
            int n = rem / 128, k = rem % 128;
            float v = (r < 8) ? W2[((size_t)r * 128 + k) * 64 + n]
                              : root2[(size_t)k * 64 + n];
            wt2[j] = f2b(v);
        }
    }
}

// ---- scan1: exclusive scan of deg2 (2048/block) + fused invc ----
__global__ void scan1_kernel(const int* __restrict__ deg, int* __restrict__ rp,
                             int* __restrict__ bsum, float* __restrict__ invc,
                             int M, int N) {
    __shared__ int s[256];
    int base = blockIdx.x * 2048;
    int t = threadIdx.x;
    int v[8]; int loc = 0;
#pragma unroll
    for (int i = 0; i < 8; ++i) {
        int idx = base + t * 8 + i;
        v[i] = (idx < M) ? deg[idx] : 0;
        loc += v[i];
    }
    int node = blockIdx.x * 256 + t;
    if (node < N) invc[node] = 1.0f / (float)max(loc, 1);
    s[t] = loc;
    __syncthreads();
    for (int off = 1; off < 256; off <<= 1) {
        int x = (t >= off) ? s[t - off] : 0;
        __syncthreads();
        s[t] += x;
        __syncthreads();
    }
    int run = s[t] - loc;
#pragma unroll
    for (int i = 0; i < 8; ++i) {
        int idx = base + t * 8 + i;
        if (idx < M) rp[idx] = run;
        run += v[i];
    }
    if (t == 255) bsum[blockIdx.x] = s[255];
}

// ---- scan2 + global min/max reduce (single block) ----
__global__ void scan2_mm(int* bsum, int nb, const float* __restrict__ bmn,
                         const float* __restrict__ bmx, float* mm) {
    __shared__ int s[256];
    __shared__ float smn[256], smx[256];
    int t = threadIdx.x;
    int v = (t < nb) ? bsum[t] : 0;
    s[t] = v;
    smn[t] = fminf(bmn[t], bmn[t + 256]);
    smx[t] = fmaxf(bmx[t], bmx[t + 256]);
    __syncthreads();
    for (int off = 1; off < 256; off <<= 1) {
        int x = (t >= off) ? s[t - off] : 0;
        __syncthreads();
        s[t] += x;
        __syncthreads();
    }
    if (t < nb) bsum[t] = s[t] - v;
    for (int r = 128; r > 0; r >>= 1) {
        if (t < r) {
            smn[t] = fminf(smn[t], smn[t + r]);
            smx[t] = fmaxf(smx[t], smx[t + r]);
        }
        __syncthreads();
    }
    if (t == 0) { mm[0] = smn[0]; mm[1] = smx[0]; }
}

__global__ void scan3_kernel(int* __restrict__ rp, const int* __restrict__ bsum, int M) {
    int i = blockIdx.x * blockDim.x + threadIdx.x;
    if (i < M) rp[i] += bsum[i >> 11];
}

// ---- CSR fill: pos = rp2[dst*8+rel]++ ; erec = bf16(w_norm)<<17 | src (4B) ----
// w >= 0 so its bf16 has sign 0 -> fits 15 bits; src < 2^17.
__global__ void fill2_kernel(const int* __restrict__ src, const int* __restrict__ dst,
                             const int* __restrict__ et, const float* __restrict__ ew,
                             const float* __restrict__ mm, int* __restrict__ rp2,
                             unsigned* __restrict__ erec, int E) {
    int e = blockIdx.x * blockDim.x + threadIdx.x;
    if (e >= E) return;
    int pos = atomicAdd(&rp2[dst[e] * R_NUM + et[e]], 1);
    float mn = mm[0], mx = mm[1];
    unsigned wq = f2b((ew[e] - mn) / (mx - mn + 1e-8f));
    erec[pos] = (wq << 17) | (unsigned)src[e];
}

// ---- gather: y[seg] = invc[n] * sum_{e in seg} w * inp[src],  seg=(n,r) ------
// 32 lanes per segment, 4 channels (8B) each: half the per-thread VALU of the
// 16-lane version, 2x TLP. Row reads 256B contiguous per edge; writes coalesced.
__global__ __launch_bounds__(256) void gather_y(
    const int* __restrict__ rp2, const unsigned* __restrict__ erec,
    const unsigned short* __restrict__ inp, const float* __restrict__ invc,
    unsigned short* __restrict__ y, int N) {
    int gid = blockIdx.x * 256 + threadIdx.x;
    int seg = gid >> 5;
    int n = seg >> 3;
    if (n >= N) return;
    int j = (gid & 31) * 4;
    int beg = (seg == 0) ? 0 : rp2[seg - 1];
    int end = rp2[seg];
    float a0 = 0.f, a1 = 0.f, a2 = 0.f, a3 = 0.f;
    for (int k = beg; k < end; ++k) {
        unsigned rec = erec[k];
        float w = __uint_as_float((rec >> 1) & 0x7FFF8000u);  // bf16 -> f32
        ushort4 v = *(const ushort4*)(inp + (size_t)(rec & 0x1FFFFu) * 128 + j);
        a0 += w * b2f(v.x); a1 += w * b2f(v.y);
        a2 += w * b2f(v.z); a3 += w * b2f(v.w);
    }
    float inv = invc[n];
    ushort4 o;
    o.x = f2b(a0 * inv); o.y = f2b(a1 * inv);
    o.z = f2b(a2 * inv); o.w = f2b(a3 * inv);
    *(ushort4*)(y + (size_t)seg * 128 + j) = o;
}

// =====================================================================
// gemm_y: out[n] = sum_{r<8} y[n][r] @ Wt[r] + inp[n] @ Wt[8] + bias
// Block = 64 nodes; stage Wt[r] + y-slice into LDS (coalesced), MFMA from
// LDS (132-short padded rows). MFMA roles (verified R4-R7): A=Wt frag,
// B=y frag, D: col=node, row=quad*4+i=out-col.
// =====================================================================
template <int NCOL, bool RELU, bool OUTB>
__global__ __launch_bounds__(256) void gemm_y(
    const unsigned short* __restrict__ y,     // N x 8 x 128 bf16
    const unsigned short* __restrict__ inp,   // N x 128 bf16 (self/root rows)
    const unsigned short* __restrict__ Wt,    // 9 x NCOL x 128 bf16
    const float* __restrict__ bias,
    unsigned short* __restrict__ outb, float* __restrict__ outf, int N)
{
    constexpr int NT = NCOL / 16;
    __shared__ unsigned short smem[64 * 132 + NCOL * 132];
    unsigned short* ys  = smem;              // 64 x 132
    unsigned short* wsd = smem + 64 * 132;   // NCOL x 132

    const int tid = threadIdx.x;
    const int w = tid >> 6, lane = tid & 63;
    const int quad = lane >> 4, l15 = lane & 15;
    const int n0 = blockIdx.x * 64;

    f32x4 acc[NT];
#pragma unroll
    for (int nt = 0; nt < NT; ++nt) acc[nt] = (f32x4){0.f, 0.f, 0.f, 0.f};

    for (int r = 0; r < 9; ++r) {
        // stage Wt[r] (NCOL x 128): coalesced 16B/lane
#pragma unroll
        for (int it = 0; it < NCOL / 16; ++it) {
            int u = tid + it * 256;
            int row = u >> 4, seg = u & 15;
            V8 v;
            v.v = *(const bf16x8*)(Wt + ((size_t)r * NCOL + row) * 128 + seg * 8);
            *(short4*)&wsd[row * 132 + seg * 8]     = v.h[0];
            *(short4*)&wsd[row * 132 + seg * 8 + 4] = v.h[1];
        }
        // stage y-slice (64 nodes x 128): r<8 from y, r==8 from inp
#pragma unroll
        for (int it = 0; it < 4; ++it) {
            int u = tid + it * 256;
            int row = u >> 4, seg = u & 15;
            int node = n0 + row;
            if (node >= N) node = N - 1;
            const unsigned short* src = (r < 8)
                ? y + ((size_t)node * R_NUM + r) * 128 + seg * 8
                : inp + (size_t)node * 128 + seg * 8;
            V8 v; v.v = *(const bf16x8*)src;
            *(short4*)&ys[row * 132 + seg * 8]     = v.h[0];
            *(short4*)&ys[row * 132 + seg * 8 + 4] = v.h[1];
        }
        __syncthreads();
        const unsigned short* yrow = ys + (size_t)(w * 16 + l15) * 132 + quad * 8;
#pragma unroll
        for (int k2 = 0; k2 < 4; ++k2) {
            V8 b;
            b.h[0] = *(const short4*)(yrow + k2 * 32);
            b.h[1] = *(const short4*)(yrow + k2 * 32 + 4);
#pragma unroll
            for (int nt = 0; nt < NT; ++nt) {
                const unsigned short* ar = wsd + (size_t)(nt * 16 + l15) * 132
                                           + k2 * 32 + quad * 8;
                V8 av;
                av.h[0] = *(const short4*)ar;
                av.h[1] = *(const short4*)(ar + 4);
                acc[nt] = __builtin_amdgcn_mfma_f32_16x16x32_bf16(av.v, b.v, acc[nt], 0, 0, 0);
            }
        }
        __syncthreads();
    }

    // epilogue: bias (+relu), LDS transpose, coalesced store (4 thr/node)
    const int gn = tid >> 2, gq = tid & 3;
    const int gnode = n0 + gn;
    if (OUTB) {
        unsigned short* stg = smem;   // 64 x 136
#pragma unroll
        for (int nt = 0; nt < NT; ++nt) {
            int c0 = nt * 16 + quad * 4;
            float4 bs = *(const float4*)(bias + c0);
            float v0 = acc[nt][0] + bs.x, v1 = acc[nt][1] + bs.y;
            float v2 = acc[nt][2] + bs.z, v3 = acc[nt][3] + bs.w;
            if (RELU) {
                v0 = fmaxf(v0, 0.f); v1 = fmaxf(v1, 0.f);
                v2 = fmaxf(v2, 0.f); v3 = fmaxf(v3, 0.f);
            }
            short4 o;
            o.x = (short)f2b(v0); o.y = (short)f2b(v1);
            o.z = (short)f2b(v2); o.w = (short)f2b(v3);
            *(short4*)&stg[(w * 16 + l15) * 136 + c0] = o;
        }
        __syncthreads();
        if (gnode < N) {
            const unsigned short* srow = stg + gn * 136 + gq * (NCOL / 4);
            unsigned short* drow = outb + (size_t)gnode * NCOL + gq * (NCOL / 4);
#pragma unroll
            for (int c = 0; c < NCOL / 32; ++c)
                *(bf16x8*)(drow + c * 8) = *(const bf16x8*)(srow + c * 8);
        }
    } else {
        float* stg = (float*)smem;    // 64 x 68 floats
#pragma unroll
        for (int nt = 0; nt < NT; ++nt) {
            int c0 = nt * 16 + quad * 4;
            float4 bs = *(const float4*)(bias + c0);
            float v0 = acc[nt][0] + bs.x, v1 = acc[nt][1] + bs.y;
            float v2 = acc[nt][2] + bs.z, v3 = acc[nt][3] + bs.w;
            if (RELU) {
                v0 = fmaxf(v0, 0.f); v1 = fmaxf(v1, 0.f);
                v2 = fmaxf(v2, 0.f); v3 = fmaxf(v3, 0.f);
            }
            *(float4*)&stg[(w * 16 + l15) * 68 + c0] = make_float4(v0, v1, v2, v3);
        }
        __syncthreads();
        if (gnode < N) {
            const float* srow = stg + gn * 68 + gq * (NCOL / 4);
            float* drow = outf + (size_t)gnode * NCOL + gq * (NCOL / 4);
#pragma unroll
            for (int c = 0; c < NCOL / 16; ++c)
                *(float4*)(drow + c * 4) = *(const float4*)(srow + c * 4);
        }
    }
}

extern "C" void kernel_launch(void* const* d_in, const int* in_sizes, int n_in,
                              void* d_out, int out_size, void* d_ws, size_t ws_size,
                              hipStream_t stream) {
    const float* x     = (const float*)d_in[0];
    const int*   ei    = (const int*)d_in[1];
    const float* ew    = (const float*)d_in[2];
    const int*   et    = (const int*)d_in[3];
    const float* W1    = (const float*)d_in[4];
    const float* root1 = (const float*)d_in[5];
    const float* bias1 = (const float*)d_in[6];
    const float* W2    = (const float*)d_in[7];
    const float* root2 = (const float*)d_in[8];
    const float* bias2 = (const float*)d_in[9];

    const int N = in_sizes[0] / F_DIM;
    const int E = in_sizes[2];
    const int M2 = N * R_NUM;
    const int* srcp = ei;
    const int* dstp = ei + E;

    // ws layout (int units unless noted):
    // mm[16] | invc[N] | deg2[8N] | rp2[8N] | bsum[256] | bmn[512] | bmx[512] |
    // erec[E] | xb[N*128 u16] | hb[N*128 u16] | wt1[9*128*128 u16] |
    // wt2[9*64*128 u16] | y[N*1024 u16]
    int* base = (int*)d_ws;
    float* mm    = (float*)base;
    float* invc  = (float*)(base + 16);
    int*   deg2  = base + 16 + N;
    int*   rp2   = deg2 + M2;
    int*   bsum  = rp2 + M2;
    float* bmn   = (float*)(bsum + 256);
    float* bmx   = bmn + 512;
    unsigned* erec = (unsigned*)(bmx + 512);
    unsigned short* xb  = (unsigned short*)(erec + E);
    unsigned short* hb  = xb + (size_t)N * 128;
    unsigned short* wt1 = hb + (size_t)N * 128;
    unsigned short* wt2 = wt1 + 9 * 128 * 128;
    unsigned short* y   = wt2 + 9 * 64 * 128;   // N * 8 * 128

    const int TB = 256;
    int blocksE = (E + TB - 1) / TB;
    int nb = (M2 + 2047) / 2048;   // 196 <= 256
    long x4 = (long)N * 128 / 4;

    // ---- setup (6 launches) ----
    hipMemsetAsync(deg2, 0, (size_t)M2 * sizeof(int), stream);
    setupA<<<512, TB, 0, stream>>>(ew, dstp, et, E, deg2, bmn, bmx,
                                   x, xb, x4, W1, root1, W2, root2, wt1, wt2);
    scan1_kernel<<<nb, TB, 0, stream>>>(deg2, rp2, bsum, invc, M2, N);
    scan2_mm<<<1, TB, 0, stream>>>(bsum, nb, bmn, bmx, mm);
    scan3_kernel<<<(M2 + TB - 1) / TB, TB, 0, stream>>>(rp2, bsum, M2);
    fill2_kernel<<<blocksE, TB, 0, stream>>>(srcp, dstp, et, ew, mm, rp2, erec, E);

    int gatB = (int)(((long)M2 * 32 + TB - 1) / TB);   // 50000
    int gB = (N + 63) / 64;                            // 782

    // ---- layer 1: 128 -> 128, relu, bf16 out ----
    gather_y<<<gatB, TB, 0, stream>>>(rp2, erec, xb, invc, y, N);
    gemm_y<H_DIM, true, true><<<gB, TB, 0, stream>>>(y, xb, wt1, bias1, hb, nullptr, N);
    // ---- layer 2: 128 -> 64, f32 out ----
    gather_y<<<gatB, TB, 0, stream>>>(rp2, erec, hb, invc, y, N);
    gemm_y<O_DIM, false, false><<<gB, TB, 0, stream>>>(y, hb, wt2, bias2, nullptr,
                                                       (float*)d_out, N);
}

// Round 9
// 317.481 us; speedup vs baseline: 1.2196x; 1.2196x over previous
//
#include <hip/hip_runtime.h>

// Problem constants: N=50000, E=600000, F=128, H=128, O=64, R=8
#define F_DIM 128
#define H_DIM 128
#define O_DIM 64
#define R_NUM 8

typedef __attribute__((ext_vector_type(8))) short bf16x8;
typedef __attribute__((ext_vector_type(4))) float f32x4;
typedef __attribute__((ext_vector_type(8))) unsigned short u16x8;

union V8 { bf16x8 v; short4 h[2]; };

__device__ __forceinline__ unsigned short f2b(float f) {
    unsigned u = __float_as_uint(f);
    u += 0x7FFFu + ((u >> 16) & 1u);   // RNE
    return (unsigned short)(u >> 16);
}
__device__ __forceinline__ float b2f(unsigned short b) {
    return __uint_as_float(((unsigned)b) << 16);
}

// ---- fused setup A: (dst,rel) degree count + per-block ew min/max ;
//      x -> bf16 ; both weight stacks transpose+convert. Grid MUST be 512. ----
__global__ __launch_bounds__(256) void setupA(
    const float* __restrict__ ew, const int* __restrict__ dst,
    const int* __restrict__ et, int E, int* __restrict__ deg2,
    float* __restrict__ bmn, float* __restrict__ bmx,
    const float* __restrict__ x, unsigned short* __restrict__ xb, long x4,
    const float* __restrict__ W1, const float* __restrict__ root1,
    const float* __restrict__ W2, const float* __restrict__ root2,
    unsigned short* __restrict__ wt1, unsigned short* __restrict__ wt2) {
    __shared__ float smn[256], smx[256];
    const int tid = threadIdx.x;
    const int gstride = gridDim.x * blockDim.x;
    int g0 = blockIdx.x * blockDim.x + tid;

    // phase 1: degree count + minmax partials
    float mn = 1e30f, mx = -1e30f;
    for (int i = g0; i < E; i += gstride) {
        atomicAdd(&deg2[dst[i] * R_NUM + et[i]], 1);
        float v = ew[i];
        mn = fminf(mn, v);
        mx = fmaxf(mx, v);
    }
    smn[tid] = mn; smx[tid] = mx;
    __syncthreads();
    for (int s = 128; s > 0; s >>= 1) {
        if (tid < s) {
            smn[tid] = fminf(smn[tid], smn[tid + s]);
            smx[tid] = fmaxf(smx[tid], smx[tid + s]);
        }
        __syncthreads();
    }
    if (tid == 0) { bmn[blockIdx.x] = smn[0]; bmx[blockIdx.x] = smx[0]; }

    // phase 2: x -> bf16 (float4 groups)
    for (long i = g0; i < x4; i += gstride) {
        float4 v = ((const float4*)x)[i];
        ushort4 o;
        o.x = f2b(v.x); o.y = f2b(v.y); o.z = f2b(v.z); o.w = f2b(v.w);
        ((ushort4*)xb)[i] = o;
    }

    // phase 3: weights -> transposed bf16
    const int n1 = 9 * 128 * 128, n2 = 9 * 64 * 128;
    for (int idx = g0; idx < n1 + n2; idx += gstride) {
        if (idx < n1) {
            int r = idx / (128 * 128), rem = idx % (128 * 128);
            int n = rem / 128, k = rem % 128;
            float v = (r < 8) ? W1[((size_t)r * 128 + k) * 128 + n]
                              : root1[(size_t)k * 128 + n];
            wt1[idx] = f2b(v);
        } else {
            int j = idx - n1;
            int r = j / (64 * 128), rem = j % (64 * 128);
            int n = rem / 128, k = rem % 128;
            float v = (r < 8) ? W2[((size_t)r * 128 + k) * 64 + n]
                              : root2[(size_t)k * 64 + n];
            wt2[j] = f2b(v);
        }
    }
}

// ---- scan1: exclusive scan of deg2 (2048/block) + fused invc ----
__global__ void scan1_kernel(const int* __restrict__ deg, int* __restrict__ rp,
                             int* __restrict__ bsum, float* __restrict__ invc,
                             int M, int N) {
    __shared__ int s[256];
    int base = blockIdx.x * 2048;
    int t = threadIdx.x;
    int v[8]; int loc = 0;
#pragma unroll
    for (int i = 0; i < 8; ++i) {
        int idx = base + t * 8 + i;
        v[i] = (idx < M) ? deg[idx] : 0;
        loc += v[i];
    }
    int node = blockIdx.x * 256 + t;
    if (node < N) invc[node] = 1.0f / (float)max(loc, 1);
    s[t] = loc;
    __syncthreads();
    for (int off = 1; off < 256; off <<= 1) {
        int x = (t >= off) ? s[t - off] : 0;
        __syncthreads();
        s[t] += x;
        __syncthreads();
    }
    int run = s[t] - loc;
#pragma unroll
    for (int i = 0; i < 8; ++i) {
        int idx = base + t * 8 + i;
        if (idx < M) rp[idx] = run;
        run += v[i];
    }
    if (t == 255) bsum[blockIdx.x] = s[255];
}

// ---- scan2 + global min/max reduce (single block) ----
__global__ void scan2_mm(int* bsum, int nb, const float* __restrict__ bmn,
                         const float* __restrict__ bmx, float* mm) {
    __shared__ int s[256];
    __shared__ float smn[256], smx[256];
    int t = threadIdx.x;
    int v = (t < nb) ? bsum[t] : 0;
    s[t] = v;
    smn[t] = fminf(bmn[t], bmn[t + 256]);
    smx[t] = fmaxf(bmx[t], bmx[t + 256]);
    __syncthreads();
    for (int off = 1; off < 256; off <<= 1) {
        int x = (t >= off) ? s[t - off] : 0;
        __syncthreads();
        s[t] += x;
        __syncthreads();
    }
    if (t < nb) bsum[t] = s[t] - v;
    for (int r = 128; r > 0; r >>= 1) {
        if (t < r) {
            smn[t] = fminf(smn[t], smn[t + r]);
            smx[t] = fmaxf(smx[t], smx[t + r]);
        }
        __syncthreads();
    }
    if (t == 0) { mm[0] = smn[0]; mm[1] = smx[0]; }
}

__global__ void scan3_kernel(int* __restrict__ rp, const int* __restrict__ bsum, int M) {
    int i = blockIdx.x * blockDim.x + threadIdx.x;
    if (i < M) rp[i] += bsum[i >> 11];
}

// ---- CSR fill: pos = rp2[dst*8+rel]++ ;
//      erec = bf16(w_norm * invc[dst])<<17 | src   (4B record)
// w_norm*invc >= 0 -> bf16 sign bit 0 -> fits 15 bits; src < 2^17.
__global__ void fill2_kernel(const int* __restrict__ src, const int* __restrict__ dst,
                             const int* __restrict__ et, const float* __restrict__ ew,
                             const float* __restrict__ mm, const float* __restrict__ invc,
                             int* __restrict__ rp2, unsigned* __restrict__ erec, int E) {
    int e = blockIdx.x * blockDim.x + threadIdx.x;
    if (e >= E) return;
    int d = dst[e];
    int pos = atomicAdd(&rp2[d * R_NUM + et[e]], 1);
    float mn = mm[0], mx = mm[1];
    unsigned wq = f2b((ew[e] - mn) / (mx - mn + 1e-8f) * invc[d]);
    erec[pos] = (wq << 17) | (unsigned)src[e];
}

// ---- gather: y[seg] = sum_{e in seg} w_premul * inp[src],  seg=(n,r) --------
// 16 lanes per segment, 8 channels (16B) each -> 1KB per wave load instr.
// 2-edge unroll: both row loads in flight before either FMA chain.
__global__ __launch_bounds__(256) void gather_y(
    const int* __restrict__ rp2, const unsigned* __restrict__ erec,
    const unsigned short* __restrict__ inp,
    unsigned short* __restrict__ y, int N) {
    int gid = blockIdx.x * 256 + threadIdx.x;
    int seg = gid >> 4;
    int n = seg >> 3;
    if (n >= N) return;
    int j = (gid & 15) * 8;
    int beg = (seg == 0) ? 0 : rp2[seg - 1];
    int end = rp2[seg];
    float acc[8] = {0.f, 0.f, 0.f, 0.f, 0.f, 0.f, 0.f, 0.f};
    int k = beg;
    for (; k + 2 <= end; k += 2) {
        unsigned r0 = erec[k], r1 = erec[k + 1];
        float w0 = __uint_as_float((r0 >> 1) & 0x7FFF8000u);
        float w1 = __uint_as_float((r1 >> 1) & 0x7FFF8000u);
        u16x8 v0 = *(const u16x8*)(inp + (size_t)(r0 & 0x1FFFFu) * 128 + j);
        u16x8 v1 = *(const u16x8*)(inp + (size_t)(r1 & 0x1FFFFu) * 128 + j);
#pragma unroll
        for (int c = 0; c < 8; ++c) acc[c] += w0 * b2f(v0[c]);
#pragma unroll
        for (int c = 0; c < 8; ++c) acc[c] += w1 * b2f(v1[c]);
    }
    if (k < end) {
        unsigned r0 = erec[k];
        float w0 = __uint_as_float((r0 >> 1) & 0x7FFF8000u);
        u16x8 v0 = *(const u16x8*)(inp + (size_t)(r0 & 0x1FFFFu) * 128 + j);
#pragma unroll
        for (int c = 0; c < 8; ++c) acc[c] += w0 * b2f(v0[c]);
    }
    u16x8 o;
#pragma unroll
    for (int c = 0; c < 8; ++c) o[c] = f2b(acc[c]);
    *(u16x8*)(y + (size_t)seg * 128 + j) = o;
}

// =====================================================================
// gemm_y: out[n] = sum_{r<8} y[n][r] @ Wt[r] + inp[n] @ Wt[8] + bias
// Block = 64 nodes; stage Wt[r] + y-slice into LDS (coalesced), MFMA from
// LDS (132-short padded rows). MFMA roles (verified R4-R8): A=Wt frag,
// B=y frag, D: col=node, row=quad*4+i=out-col.
// =====================================================================
template <int NCOL, bool RELU, bool OUTB>
__global__ __launch_bounds__(256) void gemm_y(
    const unsigned short* __restrict__ y,     // N x 8 x 128 bf16
    const unsigned short* __restrict__ inp,   // N x 128 bf16 (self/root rows)
    const unsigned short* __restrict__ Wt,    // 9 x NCOL x 128 bf16
    const float* __restrict__ bias,
    unsigned short* __restrict__ outb, float* __restrict__ outf, int N)
{
    constexpr int NT = NCOL / 16;
    __shared__ unsigned short smem[64 * 132 + NCOL * 132];
    unsigned short* ys  = smem;              // 64 x 132
    unsigned short* wsd = smem + 64 * 132;   // NCOL x 132

    const int tid = threadIdx.x;
    const int w = tid >> 6, lane = tid & 63;
    const int quad = lane >> 4, l15 = lane & 15;
    const int n0 = blockIdx.x * 64;

    f32x4 acc[NT];
#pragma unroll
    for (int nt = 0; nt < NT; ++nt) acc[nt] = (f32x4){0.f, 0.f, 0.f, 0.f};

    for (int r = 0; r < 9; ++r) {
        // stage Wt[r] (NCOL x 128): coalesced 16B/lane
#pragma unroll
        for (int it = 0; it < NCOL / 16; ++it) {
            int u = tid + it * 256;
            int row = u >> 4, seg = u & 15;
            V8 v;
            v.v = *(const bf16x8*)(Wt + ((size_t)r * NCOL + row) * 128 + seg * 8);
            *(short4*)&wsd[row * 132 + seg * 8]     = v.h[0];
            *(short4*)&wsd[row * 132 + seg * 8 + 4] = v.h[1];
        }
        // stage y-slice (64 nodes x 128): r<8 from y, r==8 from inp
#pragma unroll
        for (int it = 0; it < 4; ++it) {
            int u = tid + it * 256;
            int row = u >> 4, seg = u & 15;
            int node = n0 + row;
            if (node >= N) node = N - 1;
            const unsigned short* src = (r < 8)
                ? y + ((size_t)node * R_NUM + r) * 128 + seg * 8
                : inp + (size_t)node * 128 + seg * 8;
            V8 v; v.v = *(const bf16x8*)src;
            *(short4*)&ys[row * 132 + seg * 8]     = v.h[0];
            *(short4*)&ys[row * 132 + seg * 8 + 4] = v.h[1];
        }
        __syncthreads();
        const unsigned short* yrow = ys + (size_t)(w * 16 + l15) * 132 + quad * 8;
#pragma unroll
        for (int k2 = 0; k2 < 4; ++k2) {
            V8 b;
            b.h[0] = *(const short4*)(yrow + k2 * 32);
            b.h[1] = *(const short4*)(yrow + k2 * 32 + 4);
#pragma unroll
            for (int nt = 0; nt < NT; ++nt) {
                const unsigned short* ar = wsd + (size_t)(nt * 16 + l15) * 132
                                           + k2 * 32 + quad * 8;
                V8 av;
                av.h[0] = *(const short4*)ar;
                av.h[1] = *(const short4*)(ar + 4);
                acc[nt] = __builtin_amdgcn_mfma_f32_16x16x32_bf16(av.v, b.v, acc[nt], 0, 0, 0);
            }
        }
        __syncthreads();
    }

    // epilogue: bias (+relu), LDS transpose, coalesced store (4 thr/node)
    const int gn = tid >> 2, gq = tid & 3;
    const int gnode = n0 + gn;
    if (OUTB) {
        unsigned short* stg = smem;   // 64 x 136
#pragma unroll
        for (int nt = 0; nt < NT; ++nt) {
            int c0 = nt * 16 + quad * 4;
            float4 bs = *(const float4*)(bias + c0);
            float v0 = acc[nt][0] + bs.x, v1 = acc[nt][1] + bs.y;
            float v2 = acc[nt][2] + bs.z, v3 = acc[nt][3] + bs.w;
            if (RELU) {
                v0 = fmaxf(v0, 0.f); v1 = fmaxf(v1, 0.f);
                v2 = fmaxf(v2, 0.f); v3 = fmaxf(v3, 0.f);
            }
            short4 o;
            o.x = (short)f2b(v0); o.y = (short)f2b(v1);
            o.z = (short)f2b(v2); o.w = (short)f2b(v3);
            *(short4*)&stg[(w * 16 + l15) * 136 + c0] = o;
        }
        __syncthreads();
        if (gnode < N) {
            const unsigned short* srow = stg + gn * 136 + gq * (NCOL / 4);
            unsigned short* drow = outb + (size_t)gnode * NCOL + gq * (NCOL / 4);
#pragma unroll
            for (int c = 0; c < NCOL / 32; ++c)
                *(bf16x8*)(drow + c * 8) = *(const bf16x8*)(srow + c * 8);
        }
    } else {
        float* stg = (float*)smem;    // 64 x 68 floats
#pragma unroll
        for (int nt = 0; nt < NT; ++nt) {
            int c0 = nt * 16 + quad * 4;
            float4 bs = *(const float4*)(bias + c0);
            float v0 = acc[nt][0] + bs.x, v1 = acc[nt][1] + bs.y;
            float v2 = acc[nt][2] + bs.z, v3 = acc[nt][3] + bs.w;
            if (RELU) {
                v0 = fmaxf(v0, 0.f); v1 = fmaxf(v1, 0.f);
                v2 = fmaxf(v2, 0.f); v3 = fmaxf(v3, 0.f);
            }
            *(float4*)&stg[(w * 16 + l15) * 68 + c0] = make_float4(v0, v1, v2, v3);
        }
        __syncthreads();
        if (gnode < N) {
            const float* srow = stg + gn * 68 + gq * (NCOL / 4);
            float* drow = outf + (size_t)gnode * NCOL + gq * (NCOL / 4);
#pragma unroll
            for (int c = 0; c < NCOL / 16; ++c)
                *(float4*)(drow + c * 4) = *(const float4*)(srow + c * 4);
        }
    }
}

extern "C" void kernel_launch(void* const* d_in, const int* in_sizes, int n_in,
                              void* d_out, int out_size, void* d_ws, size_t ws_size,
                              hipStream_t stream) {
    const float* x     = (const float*)d_in[0];
    const int*   ei    = (const int*)d_in[1];
    const float* ew    = (const float*)d_in[2];
    const int*   et    = (const int*)d_in[3];
    const float* W1    = (const float*)d_in[4];
    const float* root1 = (const float*)d_in[5];
    const float* bias1 = (const float*)d_in[6];
    const float* W2    = (const float*)d_in[7];
    const float* root2 = (const float*)d_in[8];
    const float* bias2 = (const float*)d_in[9];

    const int N = in_sizes[0] / F_DIM;
    const int E = in_sizes[2];
    const int M2 = N * R_NUM;
    const int* srcp = ei;
    const int* dstp = ei + E;

    // ws layout (int units unless noted):
    // mm[16] | invc[N] | deg2[8N] | rp2[8N] | bsum[256] | bmn[512] | bmx[512] |
    // erec[E] | xb[N*128 u16] | hb[N*128 u16] | wt1[9*128*128 u16] |
    // wt2[9*64*128 u16] | y[N*1024 u16]
    int* base = (int*)d_ws;
    float* mm    = (float*)base;
    float* invc  = (float*)(base + 16);
    int*   deg2  = base + 16 + N;
    int*   rp2   = deg2 + M2;
    int*   bsum  = rp2 + M2;
    float* bmn   = (float*)(bsum + 256);
    float* bmx   = bmn + 512;
    unsigned* erec = (unsigned*)(bmx + 512);
    unsigned short* xb  = (unsigned short*)(erec + E);
    unsigned short* hb  = xb + (size_t)N * 128;
    unsigned short* wt1 = hb + (size_t)N * 128;
    unsigned short* wt2 = wt1 + 9 * 128 * 128;
    unsigned short* y   = wt2 + 9 * 64 * 128;   // N * 8 * 128

    const int TB = 256;
    int blocksE = (E + TB - 1) / TB;
    int nb = (M2 + 2047) / 2048;   // 196 <= 256
    long x4 = (long)N * 128 / 4;

    // ---- setup (6 launches) ----
    hipMemsetAsync(deg2, 0, (size_t)M2 * sizeof(int), stream);
    setupA<<<512, TB, 0, stream>>>(ew, dstp, et, E, deg2, bmn, bmx,
                                   x, xb, x4, W1, root1, W2, root2, wt1, wt2);
    scan1_kernel<<<nb, TB, 0, stream>>>(deg2, rp2, bsum, invc, M2, N);
    scan2_mm<<<1, TB, 0, stream>>>(bsum, nb, bmn, bmx, mm);
    scan3_kernel<<<(M2 + TB - 1) / TB, TB, 0, stream>>>(rp2, bsum, M2);
    fill2_kernel<<<blocksE, TB, 0, stream>>>(srcp, dstp, et, ew, mm, invc,
                                             rp2, erec, E);

    int gatB = (int)(((long)M2 * 16 + TB - 1) / TB);   // 25000
    int gB = (N + 63) / 64;                            // 782

    // ---- layer 1: 128 -> 128, relu, bf16 out ----
    gather_y<<<gatB, TB, 0, stream>>>(rp2, erec, xb, y, N);
    gemm_y<H_DIM, true, true><<<gB, TB, 0, stream>>>(y, xb, wt1, bias1, hb, nullptr, N);
    // ---- layer 2: 128 -> 64, f32 out ----
    gather_y<<<gatB, TB, 0, stream>>>(rp2, erec, hb, y, N);
    gemm_y<O_DIM, false, false><<<gB, TB, 0, stream>>>(y, hb, wt2, bias2, nullptr,
                                                       (float*)d_out, N);
}